// Round 1
// baseline (159.426 us; speedup 1.0000x reference)
//
#include <hip/hip_runtime.h>
#include <math.h>

// RankingLossListWiseDistil: B=64 rows, N=512 items, scalar f32 output.
// One kernel: 4 blocks per row (i-slabs of 128), 256 threads/block.
// Ranks via O(N^2) counting (== stable double-argsort), rel-discount via
// 52-entry LDS LUT, branchless masked pair loop, atomicAdd reduction.

#define NN 512
#define TOPN 50
#define LOG_EPS -23.025850929940457f

__global__ __launch_bounds__(256) void RankingLossListWiseDistil_kernel(
    const float* __restrict__ logits, const float* __restrict__ labels,
    float* __restrict__ out, float invB) {
  __shared__ float s_lgt[NN];    // substituted logits (LOG_EPS if invalid)
  __shared__ float s_lab[NN];    // substituted labels (0 if invalid)
  __shared__ float s_val[NN];    // 1/0 valid flag
  __shared__ float s_disc[NN];   // rank>50 ? 0 : 1/log1p(rank)
  __shared__ float s_crank[NN];  // min(rank, 51)
  __shared__ float s_rel[TOPN + 2];  // rel discount LUT by int rank_diff 0..51
  __shared__ float s_red[4];
  __shared__ float s_idcg;       // max_idcg / B

  const int b = blockIdx.x >> 2;
  const int q = blockIdx.x & 3;
  const int t = threadIdx.x;

  // ---- stage row, apply validity substitutions ----
  for (int i = t; i < NN; i += 256) {
    float lb = labels[b * NN + i];
    float lg = logits[b * NN + i];
    bool v = lb > -1000.0f;
    s_val[i] = v ? 1.0f : 0.0f;
    s_lab[i] = v ? lb : 0.0f;
    s_lgt[i] = v ? lg : LOG_EPS;
  }
  // rel-discount LUT: rd>0 ? |1/log1p(rd) - 1/log1p(rd+1)| : 0
  if (t < TOPN + 2) {
    float rd = (float)t;
    s_rel[t] = (t > 0)
        ? fabsf(1.0f / log1pf(rd) - 1.0f / log1pf(rd + 1.0f))
        : 0.0f;
  }
  __syncthreads();

  // ---- ranks (1-based, descending logits, stable tie-break by index) ----
  for (int i = t; i < NN; i += 256) {
    float sl = s_lgt[i];
    int r = 1;
#pragma unroll 8
    for (int j = 0; j < NN; ++j) {
      float slj = s_lgt[j];
      r += (slj > sl || (slj == sl && j < i)) ? 1 : 0;
    }
    float rk = (float)r;
    s_disc[i] = (rk > 50.0f) ? 0.0f : 1.0f / log1pf(rk);
    s_crank[i] = fminf(rk, 51.0f);
  }
  // ---- ideal-DCG normalizer: position-based, first 50 slots ----
  if (t == 0) {
    float md = 0.0f;
    for (int p = 1; p <= TOPN; ++p) md += s_val[p - 1] / log1pf((float)p);
    s_idcg = (md > 0.0f) ? invB / md : 0.0f;
  }
  __syncthreads();

  // ---- pairwise loss over i-slab [q*128, q*128+128) x all j ----
  float acc = 0.0f;
  const int ibase = q * (NN / 4);
  for (int idx = t; idx < (NN / 4) * NN; idx += 256) {
    int i = ibase + (idx >> 9);
    int j = idx & (NN - 1);
    float li = s_lab[i], lj = s_lab[j];
    // mask = (label_i > label_j) * valid_i * valid_j
    float m = (li > lj) ? s_val[i] * s_val[j] : 0.0f;
    float x = (s_lgt[i] - s_lgt[j]) * 0.5f;   // pairwise logit diff / TEMP
    float ld = (li - lj) * 0.5f;              // pairwise label diff / TEMP
    float tgt = __fdividef(1.0f, 1.0f + __expf(-ld));  // sigmoid
    float sp = __logf(1.0f + __expf(-x));     // softplus(-x); x in [-13.5,13.5]
    float bce = sp + (1.0f - tgt) * x;        // t*sp(-x)+(1-t)*sp(x)
    float rd = fabsf(s_crank[i] - s_crank[j]);  // exact small integer
    float w = 0.75f * s_rel[(int)rd] + 0.25f * fabsf(s_disc[i] - s_disc[j]);
    acc += bce * w * m;
  }
  acc *= s_idcg;

  // ---- block reduction: wave64 shuffle + cross-wave LDS ----
  for (int off = 32; off > 0; off >>= 1) acc += __shfl_down(acc, off, 64);
  if ((t & 63) == 0) s_red[t >> 6] = acc;
  __syncthreads();
  if (t == 0) {
    atomicAdd(out, s_red[0] + s_red[1] + s_red[2] + s_red[3]);
  }
}

extern "C" void kernel_launch(void* const* d_in, const int* in_sizes, int n_in,
                              void* d_out, int out_size, void* d_ws, size_t ws_size,
                              hipStream_t stream) {
  const float* logits = (const float*)d_in[0];
  const float* labels = (const float*)d_in[1];
  float* out = (float*)d_out;
  const int B = in_sizes[0] / NN;  // 64

  // d_out is re-poisoned to 0xAA before every launch; zero it (capturable).
  hipMemsetAsync(out, 0, sizeof(float), stream);

  dim3 grid(B * 4), block(256);
  RankingLossListWiseDistil_kernel<<<grid, block, 0, stream>>>(
      logits, labels, out, 1.0f / (float)B);
}

// Round 2
// 104.981 us; speedup vs baseline: 1.5186x; 1.5186x over previous
//
#include <hip/hip_runtime.h>
#include <math.h>

// RankingLossListWiseDistil, B=64 x N=512 -> scalar f32.
// Two-phase: prep (ranks/exps per item -> ws), then pair kernel at high
// occupancy with register-hoisted i-side and wave-uniform-broadcast j-side.
//
// Identities used (cuts 4 transcendentals/pair to 2):
//   target        = sigmoid((li-lj)/2) = Ei/(Ei+Ej),   Ei = e^{li/2}
//   softplus(-x)  = log(Gi+Gj) - hi,                   Gi = e^{gi/2}, hi = gi/2
//   bce           = softplus(-x) + (1-target)*x
//   mask          = (li>lj)*vi*vj  ==  (Ei > Ej) with E=NaN for invalid
//     (NaN compares false both ways; e^{l/2} is strictly monotone)

#define NN 512
#define TOPN 50
#define LOG_EPS -23.025850929940457f

// ws layout: float4 item[B*NN] = {G, E(or NaN), h, capped_rank}; float scale[B]

__global__ __launch_bounds__(256) void prep_kernel(
    const float* __restrict__ logits, const float* __restrict__ labels,
    float4* __restrict__ item, float* __restrict__ scale, float invB) {
  __shared__ float s_lgt[NN];
  __shared__ float s_lab[NN];
  const int b = blockIdx.x;
  const int t = threadIdx.x;

  for (int i = t; i < NN; i += 256) {
    float lb = labels[b * NN + i];
    float lg = logits[b * NN + i];
    s_lab[i] = lb;
    s_lgt[i] = (lb > -1000.0f) ? lg : LOG_EPS;
  }
  __syncthreads();

  // Counting rank == stable double-argsort: 1 + #{j: g_j>g_i} + #{j<i: g_j==g_i}
  const int i0 = t, i1 = t + 256;
  float g0 = s_lgt[i0], g1 = s_lgt[i1];
  int r0 = 1, r1 = 1;
#pragma unroll 8
  for (int j = 0; j < NN; ++j) {
    float gj = s_lgt[j];  // wave-uniform broadcast
    r0 += (gj > g0 || (gj == g0 && j < i0)) ? 1 : 0;
    r1 += (gj > g1 || (gj == g1 && j < i1)) ? 1 : 0;
  }
  {
    float lb = s_lab[i0];
    bool v = lb > -1000.0f;
    float h = g0 * 0.5f;
    float E = v ? __expf(lb * 0.5f) : __builtin_nanf("");
    item[b * NN + i0] = make_float4(__expf(h), E, h, fminf((float)r0, 51.0f));
  }
  {
    float lb = s_lab[i1];
    bool v = lb > -1000.0f;
    float h = g1 * 0.5f;
    float E = v ? __expf(lb * 0.5f) : __builtin_nanf("");
    item[b * NN + i1] = make_float4(__expf(h), E, h, fminf((float)r1, 51.0f));
  }
  // ideal-DCG normalizer: position-based first 50 slots (wave 0 only)
  if (t < 64) {
    float v = 0.0f;
    if (t < TOPN) v = (s_lab[t] > -1000.0f) ? 1.0f / log1pf((float)(t + 1)) : 0.0f;
    for (int off = 32; off > 0; off >>= 1) v += __shfl_down(v, off, 64);
    if (t == 0) scale[b] = (v > 0.0f) ? invB / v : 0.0f;
  }
}

// grid = B*16: blk -> {b = blk>>4, slab = (blk>>1)&7, jh = blk&1}
// lane = i within 64-wide slab; wave w covers j in [jh*256 + w*64, +64)
__global__ __launch_bounds__(256) void pair_kernel(
    const float4* __restrict__ item, const float* __restrict__ scale,
    float* __restrict__ out) {
  __shared__ float4 s_j[256];
  __shared__ float s_d[256];
  __shared__ float s_rel[TOPN + 2];
  __shared__ float s_red[4];

  const int blk = blockIdx.x;
  const int b = blk >> 4;
  const int slab = (blk >> 1) & 7;
  const int jh = blk & 1;
  const int t = threadIdx.x;
  const int lane = t & 63;
  const int w = t >> 6;

  // stage this block's 256-item j-range (one coalesced float4 per thread)
  float4 vjs = item[b * NN + jh * 256 + t];
  s_j[t] = vjs;
  s_d[t] = (vjs.w <= 50.0f) ? 1.0f / log1pf(vjs.w) : 0.0f;
  if (t < TOPN + 2) {
    float rd = (float)t;
    s_rel[t] = (t > 0)
        ? fabsf(1.0f / log1pf(rd) - 1.0f / log1pf(rd + 1.0f))
        : 0.0f;
  }
  // i-side in registers
  float4 vi = item[b * NN + slab * 64 + lane];
  const float Gi = vi.x, Ei = vi.y, hi = vi.z, cri = vi.w;
  const float di = (cri <= 50.0f) ? 1.0f / log1pf(cri) : 0.0f;
  const float sc = scale[b];
  __syncthreads();

  float acc = 0.0f;
  const int jbase = w * 64;
#pragma unroll 4
  for (int jj = 0; jj < 64; ++jj) {
    float4 v = s_j[jbase + jj];   // wave-uniform -> LDS broadcast
    float dj = s_d[jbase + jj];   // wave-uniform -> LDS broadcast
    float e = Ei + v.y;
    float omt = __fdividef(v.y, e);          // 1 - target (NaN if invalid)
    float x = hi - v.z;                       // (gi - gj)/2
    float sp = __logf(Gi + v.x) - hi;         // softplus(-x)
    float bce = fmaf(omt, x, sp);
    float rdiff = fabsf(cri - v.w);           // exact small integer
    float wgt = fmaf(0.25f, fabsf(di - dj), 0.75f * s_rel[(int)rdiff]);
    acc += (Ei > v.y) ? bce * wgt : 0.0f;     // cndmask kills NaN lanes
  }
  acc *= sc;

  for (int off = 32; off > 0; off >>= 1) acc += __shfl_down(acc, off, 64);
  if (lane == 0) s_red[w] = acc;
  __syncthreads();
  if (t == 0) atomicAdd(out, s_red[0] + s_red[1] + s_red[2] + s_red[3]);
}

extern "C" void kernel_launch(void* const* d_in, const int* in_sizes, int n_in,
                              void* d_out, int out_size, void* d_ws, size_t ws_size,
                              hipStream_t stream) {
  const float* logits = (const float*)d_in[0];
  const float* labels = (const float*)d_in[1];
  float* out = (float*)d_out;
  const int B = in_sizes[0] / NN;  // 64

  float4* item = (float4*)d_ws;
  float* scale = (float*)((char*)d_ws + (size_t)B * NN * sizeof(float4));

  hipMemsetAsync(out, 0, sizeof(float), stream);
  prep_kernel<<<dim3(B), dim3(256), 0, stream>>>(logits, labels, item, scale,
                                                 1.0f / (float)B);
  pair_kernel<<<dim3(B * 16), dim3(256), 0, stream>>>(item, scale, out);
}

// Round 3
// 89.106 us; speedup vs baseline: 1.7892x; 1.1782x over previous
//
#include <hip/hip_runtime.h>
#include <math.h>

// RankingLossListWiseDistil, B=64 x N=512 -> scalar f32.
// SINGLE fused kernel, NO d_ws (Round-2 evidence: using d_ws adds a 256 MiB
// 0xAA poison fill (~40 us) to the timed path).
//
// Grid = B*8 blocks, 256 threads. Block (b, slab): i in [slab*64, +64) x all j.
// Ranks recomputed per block (8x redundant) but cheap: sortable u64 keys ->
// rank = 1 + #{K_j > K_i} (== stable double-argsort incl. tie-break), one
// u64-compare per pair, keys streamed as wave-uniform ds_read_b128.
//
// Identities (2 transcendentals per pair instead of 4):
//   target       = sigmoid((li-lj)/2) = Ei/(Ei+Ej),  E = e^{lab/2} (NaN if invalid)
//   softplus(-x) = log(Gi+Gj) - hi,                  G = e^{g/2},  h = g/2
//   bce          = softplus(-x) + (1-target)*x
//   mask         = (li>lj)*vi*vj  ==  (Ei > Ej)   (NaN-encoded invalids fail both ways)

#define NN 512
#define TOPN 50
#define LOG_EPS -23.025850929940457f

__global__ __launch_bounds__(256) void fused_kernel(
    const float* __restrict__ logits, const float* __restrict__ labels,
    float* __restrict__ out, float invB) {
  __shared__ unsigned long long s_key[NN];  // monotonic_bits(g)<<32 | (511-i)
  __shared__ float4 s_item[NN];             // {G, E|NaN, h, capped_rank}
  __shared__ float s_d[NN];                 // per-item discount
  __shared__ float s_rel[TOPN + 2];         // rel-discount LUT by int rank_diff
  __shared__ float s_red[4];
  __shared__ float s_idcg;

  const int blk = blockIdx.x;
  const int b = blk >> 3;
  const int slab = blk & 7;
  const int t = threadIdx.x;

  // ---- stage: thread t owns items t and t+256 (coalesced loads) ----
  const int i0 = t, i1 = t + 256;
  const float lb0 = labels[b * NN + i0], lg0 = logits[b * NN + i0];
  const float lb1 = labels[b * NN + i1], lg1 = logits[b * NN + i1];
  const bool v0 = lb0 > -1000.0f, v1 = lb1 > -1000.0f;
  const float g0 = v0 ? lg0 : LOG_EPS;
  const float g1 = v1 ? lg1 : LOG_EPS;
  // order-preserving float->uint map (valid for all finite floats)
  unsigned int u0 = __float_as_uint(g0);
  unsigned int u1 = __float_as_uint(g1);
  u0 ^= (unsigned)(((int)u0 >> 31)) | 0x80000000u;
  u1 ^= (unsigned)(((int)u1 >> 31)) | 0x80000000u;
  const unsigned long long K0 =
      ((unsigned long long)u0 << 32) | (unsigned)(NN - 1 - i0);
  const unsigned long long K1 =
      ((unsigned long long)u1 << 32) | (unsigned)(NN - 1 - i1);
  s_key[i0] = K0;
  s_key[i1] = K1;
  if (t < TOPN + 2) {
    float rd = (float)t;
    s_rel[t] = (t > 0)
        ? fabsf(1.0f / log1pf(rd) - 1.0f / log1pf(rd + 1.0f))
        : 0.0f;
  }
  __syncthreads();

  // ---- ideal-DCG normalizer (position-based, first 50 slots; wave 0) ----
  if (t < 64) {
    float v = (t < TOPN && lb0 > -1000.0f) ? 1.0f / log1pf((float)(t + 1)) : 0.0f;
    for (int off = 32; off > 0; off >>= 1) v += __shfl_down(v, off, 64);
    if (t == 0) s_idcg = (v > 0.0f) ? invB / v : 0.0f;
  }

  // ---- counting ranks: rank_i = 1 + #{j: K_j > K_i} ----
  int r0 = 1, r1 = 1;
  const ulonglong2* kp = (const ulonglong2*)s_key;
#pragma unroll 8
  for (int k = 0; k < NN / 2; ++k) {
    ulonglong2 kk = kp[k];  // wave-uniform -> LDS broadcast b128
    r0 += (kk.x > K0) ? 1 : 0;
    r0 += (kk.y > K0) ? 1 : 0;
    r1 += (kk.x > K1) ? 1 : 0;
    r1 += (kk.y > K1) ? 1 : 0;
  }
  {
    const float h0 = g0 * 0.5f, h1 = g1 * 0.5f;
    const float cr0 = fminf((float)r0, 51.0f);
    const float cr1 = fminf((float)r1, 51.0f);
    s_item[i0] = make_float4(__expf(h0),
                             v0 ? __expf(lb0 * 0.5f) : __builtin_nanf(""), h0, cr0);
    s_item[i1] = make_float4(__expf(h1),
                             v1 ? __expf(lb1 * 0.5f) : __builtin_nanf(""), h1, cr1);
    s_d[i0] = (r0 <= TOPN) ? 1.0f / log1pf(cr0) : 0.0f;
    s_d[i1] = (r1 <= TOPN) ? 1.0f / log1pf(cr1) : 0.0f;
  }
  __syncthreads();

  // ---- pairwise loss: lane = i in slab, wave w covers j in [w*128, +128) ----
  const int lane = t & 63;
  const int w = t >> 6;
  const float4 vi = s_item[slab * 64 + lane];
  const float Gi = vi.x, Ei = vi.y, hi = vi.z, cri = vi.w;
  const float di = s_d[slab * 64 + lane];
  const float sc = s_idcg;

  float acc = 0.0f;
  const int j0 = w * 128;
#pragma unroll 4
  for (int jj = j0; jj < j0 + 128; ++jj) {
    float4 v = s_item[jj];   // wave-uniform -> broadcast b128
    float dj = s_d[jj];      // wave-uniform -> broadcast b32
    float omt = __fdividef(v.y, Ei + v.y);   // 1 - target (NaN if invalid)
    float x = hi - v.z;                      // (gi - gj)/2
    float sp = __logf(Gi + v.x) - hi;        // softplus(-x)
    float bce = fmaf(omt, x, sp);
    float rdiff = fabsf(cri - v.w);          // exact small integer
    float wgt = fmaf(0.25f, fabsf(di - dj), 0.75f * s_rel[(int)rdiff]);
    acc += (Ei > v.y) ? bce * wgt : 0.0f;    // cndmask kills masked/NaN lanes
  }
  acc *= sc;

  // ---- block reduction + one atomic ----
  for (int off = 32; off > 0; off >>= 1) acc += __shfl_down(acc, off, 64);
  if (lane == 0) s_red[w] = acc;
  __syncthreads();
  if (t == 0) atomicAdd(out, s_red[0] + s_red[1] + s_red[2] + s_red[3]);
}

extern "C" void kernel_launch(void* const* d_in, const int* in_sizes, int n_in,
                              void* d_out, int out_size, void* d_ws, size_t ws_size,
                              hipStream_t stream) {
  const float* logits = (const float*)d_in[0];
  const float* labels = (const float*)d_in[1];
  float* out = (float*)d_out;
  const int B = in_sizes[0] / NN;  // 64

  // d_out re-poisoned to 0xAA before every launch; zero it (graph-capturable).
  hipMemsetAsync(out, 0, sizeof(float), stream);
  fused_kernel<<<dim3(B * 8), dim3(256), 0, stream>>>(logits, labels, out,
                                                      1.0f / (float)B);
}

// Round 4
// 69.925 us; speedup vs baseline: 2.2800x; 1.2743x over previous
//
#include <hip/hip_runtime.h>
#include <math.h>

// RankingLossListWiseDistil, B=64 x N=512 -> scalar f32. Single fused kernel.
//
// KEY SPARSITY: weight == 0 unless min(rank_i, rank_j) <= 50:
//   both ranks>50 -> d_i=d_j=0 (abs part 0) and capped ranks both 51
//   (rank_diff=0 -> rel part 0). So only pairs touching the top-50 matter:
//   50*512 pairs/row instead of 512^2 (10x less pair work).
//
// SYMMETRY: bce(i,j) = sp(-x)+(1-t)x is symmetric under i<->j (sp(x)=sp(-x)+x,
// t->1-t), and the weight is symmetric; the reference mask picks exactly one
// orientation per unordered pair. So enumerate t in T(top-50) x j in all,
// mask = labels-differ-and-valid = (Et>Ej)||(Ej>Et) (NaN-encoded invalids
// fail both), and multiply by 0.5 when both in T (those pairs enumerated 2x).
//
// Identities (per-item precompute): E=e^{lab/2}|NaN, G=e^{g/2}, h=g/2:
//   1-target = Ej/(Et+Ej);  softplus(-x) = log(Gt+Gj) - ht;  bce = sp+(1-t)x
//
// Ranks: counting vs sortable u64 keys (monotone float bits | (511-i)) ==
// stable double-argsort. Only top-50 need exact rank; rest get cr=51, d=0.
//
// Grid = B*4 (1 block/CU): block (b,slab) owns j in [slab*128, +128).

#define NN 512
#define TOPN 50
#define LOG_EPS -23.025850929940457f

__global__ __launch_bounds__(256) void fused_kernel(
    const float* __restrict__ logits, const float* __restrict__ labels,
    float* __restrict__ out, float invB) {
  __shared__ unsigned long long s_key[NN];  // sortable keys
  __shared__ float4 s_f4[NN];               // {G, E|NaN, h, d}
  __shared__ float s_cr[NN];                // capped rank
  __shared__ float4 s_T[TOPN];              // rank r item at s_T[r-1]
  __shared__ float s_rel[TOPN + 2];         // rel-discount LUT by int rankdiff
  __shared__ float s_red[4];
  __shared__ float s_idcg;

  const int blk = blockIdx.x;
  const int b = blk >> 2;
  const int slab = blk & 3;
  const int t = threadIdx.x;

  // ---- stage: thread t owns items t and t+256 (coalesced) ----
  const int i0 = t, i1 = t + 256;
  const float lb0 = labels[b * NN + i0], lg0 = logits[b * NN + i0];
  const float lb1 = labels[b * NN + i1], lg1 = logits[b * NN + i1];
  const bool v0 = lb0 > -1000.0f, v1 = lb1 > -1000.0f;
  const float g0 = v0 ? lg0 : LOG_EPS;
  const float g1 = v1 ? lg1 : LOG_EPS;
  unsigned int u0 = __float_as_uint(g0);
  unsigned int u1 = __float_as_uint(g1);
  u0 ^= (unsigned)(((int)u0 >> 31)) | 0x80000000u;  // order-preserving map
  u1 ^= (unsigned)(((int)u1 >> 31)) | 0x80000000u;
  const unsigned long long K0 =
      ((unsigned long long)u0 << 32) | (unsigned)(NN - 1 - i0);
  const unsigned long long K1 =
      ((unsigned long long)u1 << 32) | (unsigned)(NN - 1 - i1);
  s_key[i0] = K0;
  s_key[i1] = K1;
  if (t < TOPN + 2) {
    float rd = (float)t;
    s_rel[t] = (t > 0)
        ? fabsf(1.0f / log1pf(rd) - 1.0f / log1pf(rd + 1.0f))
        : 0.0f;
  }
  __syncthreads();

  // ---- ideal-DCG normalizer (position-based, first 50 slots; wave 0) ----
  if (t < 64) {
    float v = (t < TOPN && lb0 > -1000.0f) ? 1.0f / log1pf((float)(t + 1)) : 0.0f;
    for (int off = 32; off > 0; off >>= 1) v += __shfl_down(v, off, 64);
    if (t == 0) s_idcg = (v > 0.0f) ? invB / v : 0.0f;
  }

  // ---- counting ranks: rank = 1 + #{j: K_j > K_i} (stable argsort equiv) ----
  int r0 = 1, r1 = 1;
  const ulonglong2* kp = (const ulonglong2*)s_key;
#pragma unroll 8
  for (int k = 0; k < NN / 2; ++k) {
    ulonglong2 kk = kp[k];  // wave-uniform -> LDS broadcast b128
    r0 += (kk.x > K0) ? 1 : 0;
    r0 += (kk.y > K0) ? 1 : 0;
    r1 += (kk.x > K1) ? 1 : 0;
    r1 += (kk.y > K1) ? 1 : 0;
  }
  {
    const float h0 = g0 * 0.5f, h1 = g1 * 0.5f;
    const float G0 = __expf(h0), G1 = __expf(h1);
    const float E0 = v0 ? __expf(lb0 * 0.5f) : __builtin_nanf("");
    const float E1 = v1 ? __expf(lb1 * 0.5f) : __builtin_nanf("");
    const float d0 = (r0 <= TOPN) ? 1.0f / log1pf((float)r0) : 0.0f;
    const float d1 = (r1 <= TOPN) ? 1.0f / log1pf((float)r1) : 0.0f;
    float4 f0 = make_float4(G0, E0, h0, d0);
    float4 f1 = make_float4(G1, E1, h1, d1);
    s_f4[i0] = f0;
    s_f4[i1] = f1;
    s_cr[i0] = fminf((float)r0, 51.0f);
    s_cr[i1] = fminf((float)r1, 51.0f);
    if (r0 <= TOPN) s_T[r0 - 1] = f0;  // exactly 50 writes block-wide
    if (r1 <= TOPN) s_T[r1 - 1] = f1;
  }
  __syncthreads();

  // ---- sparse pair loop: thread's own j fixed, iterate 25 T-items ----
  const int j = slab * 128 + (t & 127);
  const float4 vj = s_f4[j];
  const float Gj = vj.x, Ej = vj.y, hj = vj.z, dj = vj.w;
  const float crj = s_cr[j];
  const float dupj = (crj <= 50.0f) ? 0.5f : 1.0f;  // T x T counted twice
  const int tt0 = (t >> 7) * 25;  // waves 0-1: ranks 1..25; waves 2-3: 26..50
  float acc = 0.0f;
#pragma unroll 5
  for (int k = 0; k < 25; ++k) {
    const int tt = tt0 + k;
    float4 vt = s_T[tt];          // wave-uniform -> LDS broadcast b128
    float crt = (float)(tt + 1);  // rank is the index: cr_t = tt+1
    float omt = __fdividef(Ej, vt.y + Ej);  // 1 - target  (t,j orientation)
    float x = vt.z - hj;                    // (gt - gj)/2
    float sp = __logf(vt.x + Gj) - vt.z;    // softplus(-x)
    float bce = fmaf(omt, x, sp);
    float rdiff = fabsf(crt - crj);         // exact small integer in [0,50]
    float w = fmaf(0.25f, fabsf(vt.w - dj), 0.75f * s_rel[(int)rdiff]);
    bool m = (vt.y > Ej) || (Ej > vt.y);    // labels differ & both valid
    acc += m ? bce * w * dupj : 0.0f;       // cndmask kills NaN lanes
  }
  acc *= s_idcg;

  // ---- block reduction + one atomic ----
  const int lane = t & 63;
  const int w = t >> 6;
  for (int off = 32; off > 0; off >>= 1) acc += __shfl_down(acc, off, 64);
  if (lane == 0) s_red[w] = acc;
  __syncthreads();
  if (t == 0) atomicAdd(out, s_red[0] + s_red[1] + s_red[2] + s_red[3]);
}

extern "C" void kernel_launch(void* const* d_in, const int* in_sizes, int n_in,
                              void* d_out, int out_size, void* d_ws, size_t ws_size,
                              hipStream_t stream) {
  const float* logits = (const float*)d_in[0];
  const float* labels = (const float*)d_in[1];
  float* out = (float*)d_out;
  const int B = in_sizes[0] / NN;  // 64

  // d_out re-poisoned to 0xAA before every launch; zero it (graph-capturable).
  hipMemsetAsync(out, 0, sizeof(float), stream);
  fused_kernel<<<dim3(B * 4), dim3(256), 0, stream>>>(logits, labels, out,
                                                      1.0f / (float)B);
}